// Round 10
// baseline (129.942 us; speedup 1.0000x reference)
//
#include <hip/hip_runtime.h>

namespace {

typedef float v2f __attribute__((ext_vector_type(2)));

constexpr int LMAX  = 10;
constexpr int NPART = 4;
// Register-balanced 4-way partition (packed acc = 2 VGPR/slot):
// P0{3,10}=34 acc, P1{2,4,9}=40, P2{1,5,8}=37, P3{0,6,7}=35.
constexpr int PART_OF_L[LMAX + 1] = {3, 2, 1, 0, 1, 2, 3, 3, 2, 1, 0};
constexpr double PI_D = 3.14159265358979323846;

constexpr double dfact(int n) {
    double r = 1.0;
    for (int i = 2; i <= n; ++i) r *= (double)i;
    return r;
}

constexpr double csqrt(double x) {
    if (x <= 0.0) return 0.0;
    double g = x > 1.0 ? x : 1.0;
    for (int i = 0; i < 100; ++i) g = 0.5 * (g + x / g);
    return g;
}

constexpr double FACT[LMAX + 1] = {1., 1., 2., 6., 24., 120., 720., 5040., 40320., 362880., 3628800.};

// ---- global moment layout in workspace (same as R6/R7) --------------------
//   clm_r(l,m) = scale * sum_q c(l,m,q) * (M_{q+m,l} - N_{q,l})
//   M_{p,l} = sum_pts Re(z1^p)^2 * w0 * r^l     (66 entries)
//   N_{q,l} = sum_pts Im(z1^q)^2 * w0 * r^l     (25 entries, q>=1)
constexpr int NM_M = 66;
constexpr int mi(int p, int l) { return l * (l + 1) / 2 + p; }
constexpr int ni_base(int l) {
    int c = 0;
    for (int ll = 0; ll < l; ++ll) c += ll / 2;
    return c;
}
constexpr int ni(int q, int l) { return NM_M + ni_base(l) + (q - 1); }
constexpr int NM_N   = 25;
constexpr int NMOM   = NM_M + NM_N;  // 91
constexpr int ZSLOT  = NMOM;         // always-zero ws slot (index 91)
constexpr int CSLOT  = NMOM + 1;     // done-block counter (index 92)
constexpr int WS_FLOATS = NMOM + 2;  // 93

// ---- per-part helpers ------------------------------------------------------
constexpr int part_lmax(int part) {
    int mx = 0;
    for (int l = 0; l <= LMAX; ++l)
        if (PART_OF_L[l] == part) mx = l;
    return mx;
}
constexpr int nls(int part) {
    int c = 0;
    for (int l = 0; l <= LMAX; ++l)
        if (PART_OF_L[l] == part) ++c;
    return c;
}
constexpr int lidx(int part, int l) {
    int c = 0;
    for (int ll = 0; ll < l; ++ll)
        if (PART_OF_L[ll] == part) ++c;
    return c;
}
constexpr int part_ls(int part, int k) {
    int c = 0;
    for (int l = 0; l <= LMAX; ++l)
        if (PART_OF_L[l] == part) {
            if (c == k) return l;
            ++c;
        }
    return -1;
}
constexpr int nM(int part) {
    int c = 0;
    for (int l = 0; l <= LMAX; ++l)
        if (PART_OF_L[l] == part) c += l + 1;
    return c;
}
constexpr int nN(int part) {
    int c = 0;
    for (int l = 0; l <= LMAX; ++l)
        if (PART_OF_L[l] == part) c += l / 2;
    return c;
}
constexpr int nMom(int part) { return nM(part) + nN(part); }
constexpr int nI(int part) {
    int c = 0;
    for (int l = 0; l <= LMAX; ++l)
        if (PART_OF_L[l] == part) c += l;
    return c;
}
constexpr int nAcc(int part) { return nMom(part) + nI(part); }

constexpr int locM(int part, int p, int l) {
    int c = 0;
    for (int ll = 0; ll < l; ++ll)
        if (PART_OF_L[ll] == part) c += ll + 1;
    return c + p;
}
constexpr int locN(int part, int q, int l) {
    int c = nM(part);
    for (int ll = 0; ll < l; ++ll)
        if (PART_OF_L[ll] == part) c += ll / 2;
    return c + (q - 1);
}
constexpr int locI(int part, int m, int l) {
    int c = nMom(part);
    for (int ll = 0; ll < l; ++ll)
        if (PART_OF_L[ll] == part) c += ll;
    return c + (m - 1);
}

constexpr int MAXMOM = 25;  // P1: 18 M + 7 N
constexpr int MAXIMG = 15;  // P1

// Horner coefficient for the collapsed imag sum: (-1)^q / ((q+m)! q! (l-m-2q)!)
constexpr float ci_coef(int l, int m, int q) {
    const double c = 1.0 / (FACT[q + m] * FACT[q] * FACT[l - m - 2 * q]);
    return (q & 1) ? (float)(-c) : (float)c;
}

struct PartTab {
    short wsmap[NPART][MAXMOM];  // local moment slot -> global ws index
    int   omap[NPART][MAXIMG];   // local imag slot -> out index
    float oscl[NPART][MAXIMG];   // imag output scale (sqrt2*(-1)^m, T==1 fold)
};

constexpr PartTab make_pt() {
    PartTab t{};
    for (int part = 0; part < NPART; ++part) {
        for (int l = 0; l <= LMAX; ++l) {
            if (PART_OF_L[l] != part) continue;
            for (int p = 0; p <= l; ++p) t.wsmap[part][locM(part, p, l)] = (short)mi(p, l);
            for (int q = 1; q <= l / 2; ++q) t.wsmap[part][locN(part, q, l)] = (short)ni(q, l);
            for (int m = 1; m <= l; ++m) {
                const int    k     = locI(part, m, l) - nMom(part);
                const double scale = csqrt(dfact(l + m) * dfact(l - m)) * csqrt((2 * l + 1) / (4.0 * PI_D));
                const double f     = csqrt(2.0) * ((m & 1) ? -1.0 : 1.0);
                const double fold  = ((l - m) <= 1) ? 1.0 / (dfact(m) * dfact(l - m)) : 1.0;
                t.omap[part][k] = l * l + l - m;
                t.oscl[part][k] = (float)(f * scale * fold);
            }
        }
    }
    return t;
}

// Combine table: per real output slot, the q-term list over moments.
struct CombTab {
    int   out[66];
    float scale[66];
    int   nt[66];
    float c[66][6];
    short mIx[66][6];
    short nIx[66][6];
};

constexpr CombTab make_comb() {
    CombTab t{};
    int k = 0;
    for (int l = 0; l <= LMAX; ++l) {
        for (int m = 0; m <= l; ++m) {
            const double scale = csqrt(dfact(l + m) * dfact(l - m)) * csqrt((2 * l + 1) / (4.0 * PI_D));
            const double f     = (m == 0) ? 1.0 : csqrt(2.0) * ((m & 1) ? -1.0 : 1.0);
            t.out[k]   = (m == 0) ? l * l + l : l * l + l + m;
            t.scale[k] = (float)(f * scale);
            const int Q = (l - m) / 2;
            t.nt[k]     = Q + 1;
            for (int q = 0; q <= Q; ++q) {
                const double c = 1.0 / (FACT[q + m] * FACT[q] * FACT[l - m - 2 * q]);
                t.c[k][q]   = (float)c;
                t.mIx[k][q] = (short)mi(q + m, l);
                t.nIx[k][q] = (short)(q >= 1 ? ni(q, l) : ZSLOT);
            }
            ++k;
        }
    }
    return t;
}

__constant__ PartTab c_pt = make_pt();
__constant__ CombTab c_cb = make_comb();

// ---- forced-packed fp32 primitives ----------------------------------------
// R9's isolated pk pin was null; issue-math (23M issued vs ~9M static packed)
// says the compiler SCALARIZES v2f math (2 scalar fmas per op), and isolated
// pk islands just add pack/unpack seams.  These wrappers force the VOP3P
// encodings end-to-end on every constant-free op (VOP3P can't take literals,
// so constant-consuming fmas — the imag Horner — stay compiler-lowered where
// s_mov+2*v_fma is already optimal).  Packed regs are addressable as scalar
// halves, so mixing packed and scalar code costs zero moves.
__device__ __forceinline__ v2f pk_mul(v2f a, v2f b) {
    v2f d;
    asm("v_pk_mul_f32 %0, %1, %2" : "=v"(d) : "v"(a), "v"(b));
    return d;
}
__device__ __forceinline__ v2f pk_fma(v2f a, v2f b, v2f c) {
    v2f d;
    asm("v_pk_fma_f32 %0, %1, %2, %3" : "=v"(d) : "v"(a), "v"(b), "v"(c));
    return d;
}
__device__ __forceinline__ void pk_acc(v2f& d, v2f a, v2f b) {
    asm("v_pk_fma_f32 %0, %1, %2, %0" : "+v"(d) : "v"(a), "v"(b));
}

// Load the point pair {2*ip, 2*ip+1} into packed X/Y/Z (point j in half j).
// OOB points zero-fill; zero points contribute exactly zero (w0 = 0).
__device__ __forceinline__ void load_pair(const float* __restrict__ pos, int ip, int n,
                                          v2f& X, v2f& Y, v2f& Z) {
    const int i0 = 2 * ip;
    if (i0 + 1 < n) {
        const float2* p2 = reinterpret_cast<const float2*>(pos + 3 * i0);
        const float2  a = p2[0], b = p2[1], d = p2[2];
        X.x = a.x; X.y = b.y;
        Y.x = a.y; Y.y = d.x;
        Z.x = b.x; Z.y = d.y;
    } else if (i0 < n) {
        X.x = pos[3 * i0]; Y.x = pos[3 * i0 + 1]; Z.x = pos[3 * i0 + 2];
        X.y = 0.f; Y.y = 0.f; Z.y = 0.f;
    } else {
        X = (v2f)(0.f); Y = (v2f)(0.f); Z = (v2f)(0.f);
    }
}

}  // namespace

// R7 chassis exactly (moment factorization, 4 parts, serial z-chain,
// 3 blocks/CU) with every constant-free v2f op forced to v_pk_* encodings.
template <int PART>
__device__ __forceinline__ void sht_part(const float* __restrict__ pos, float* __restrict__ out,
                                         float* __restrict__ ws, int n, int nblk) {
    constexpr int PL  = part_lmax(PART);
    constexpr int QX  = PL / 2;
    constexpr int NL  = nls(PART);
    constexpr int NMO = nMom(PART);
    constexpr int NAC = nAcc(PART);

    v2f acc[NAC];
#pragma unroll
    for (int k = 0; k < NAC; ++k) acc[k] = (v2f)(0.f);

    const int bid    = (int)(blockIdx.x >> 2);
    const int tid    = bid * 256 + (int)threadIdx.x;
    const int stride = nblk * 256;  // in pairs
    const int npair  = (n + 1) >> 1;

    v2f X, Y, Z;
    int ip = tid;
    load_pair(pos, ip, n, X, Y, Z);

    while (ip < npair) {
        // software-pipelined prefetch of the next pair
        const int inext = ip + stride;
        v2f       nX, nY, nZ;
        load_pair(pos, inext, n, nX, nY, nZ);

        const v2f r2 = pk_fma(Z, Z, pk_fma(Y, Y, pk_mul(X, X)));
        v2f       nrm;
        nrm.x = sqrtf(r2.x);
        nrm.y = sqrtf(r2.y);
        v2f w0;
        w0.x = (nrm.x > 0.f) ? Z.x : 0.f;  // x0 * mask
        w0.y = (nrm.y > 0.f) ? Z.y : 0.f;

        const v2f half_neg = (v2f)(-0.5f);  // loop-invariant, hoisted
        const v2f ar  = pk_mul(half_neg, X);
        const v2f ai  = pk_mul(half_neg, Y);
        v2f       nai;
        nai.x = -ai.x;
        nai.y = -ai.y;
        const v2f rho = pk_fma(ai, ai, pk_mul(ar, ar));  // |z1|^2

        // wl[k] = w0 * nrm^l via binary decomposition (parts mix parities).
        v2f wl[NL];
        {
            const v2f p2v = pk_mul(nrm, nrm);
            const v2f p4v = pk_mul(p2v, p2v);
            const v2f p8v = pk_mul(p4v, p4v);
#pragma unroll
            for (int k = 0; k < NL; ++k) {
                const int l = part_ls(PART, k);  // compile-time
                v2f       t = w0;
                if (l & 1) t = pk_mul(t, nrm);
                if (l & 2) t = pk_mul(t, p2v);
                if (l & 4) t = pk_mul(t, p4v);
                if (l & 8) t = pk_mul(t, p8v);
                wl[k] = t;
            }
        }

        // p-major rolling powers of z1: consume sr_p/si_p immediately into
        // moment accumulators; only zi[] is tabled (needed by imag pass).
        v2f zi[PL + 1];
        v2f zrc = (v2f)(1.f), zic = (v2f)(0.f);
#pragma unroll
        for (int p = 0; p <= PL; ++p) {
            if (p) {
                const v2f nr = pk_fma(nai, zic, pk_mul(ar, zrc));
                zic          = pk_fma(ai, zrc, pk_mul(ar, zic));
                zrc          = nr;
            }
            zi[p] = zic;
            const v2f srp = pk_mul(zrc, zrc);
#pragma unroll
            for (int l = 0; l <= LMAX; ++l)
                if (PART_OF_L[l] == PART && l >= p)
                    pk_acc(acc[locM(PART, p, l)], srp, wl[lidx(PART, l)]);
            if (p >= 1 && p <= QX) {
                const v2f sip = pk_mul(zic, zic);
#pragma unroll
                for (int l = 0; l <= LMAX; ++l)
                    if (PART_OF_L[l] == PART && l >= 2 * p)
                        pk_acc(acc[locN(PART, p, l)], sip, wl[lidx(PART, l)]);
            }
        }

        // imag pass: acc_I(l,m) += zi[m] * Horner_q(+-c * rho^q) * wrl
        // (constant-heavy -> left to the compiler: s_mov const + v_fma x2
        //  per step is already the cheapest lowering)
#pragma unroll
        for (int l = 0; l <= LMAX; ++l) {
            if (PART_OF_L[l] != PART) continue;
            const v2f wrl = wl[lidx(PART, l)];
#pragma unroll
            for (int m = 1; m <= l; ++m) {
                const int Q = (l - m) >> 1;
                if (Q == 0) {
                    pk_acc(acc[locI(PART, m, l)], zi[m], wrl);  // coeff in oscl
                } else {
                    v2f tq = (v2f)(ci_coef(l, m, Q));
#pragma unroll
                    for (int q = Q - 1; q >= 0; --q) tq = tq * rho + ci_coef(l, m, q);
                    pk_acc(acc[locI(PART, m, l)], pk_mul(tq, zi[m]), wrl);
                }
            }
        }

        ip = inext;
        X  = nX;
        Y  = nY;
        Z  = nZ;
    }

    // Fold packed halves, then wave shuffle reduction, then cross-wave LDS.
    __shared__ float red[4][NAC];
    const int lane = threadIdx.x & 63;
    const int wav  = threadIdx.x >> 6;
#pragma unroll
    for (int k = 0; k < NAC; ++k) {
        float v = acc[k].x + acc[k].y;
#pragma unroll
        for (int off = 32; off > 0; off >>= 1) v += __shfl_down(v, off, 64);
        if (lane == 0) red[wav][k] = v;
    }
    __syncthreads();
    if ((int)threadIdx.x < NAC) {
        const int   k = (int)threadIdx.x;
        const float v = red[0][k] + red[1][k] + red[2][k] + red[3][k];
        if (k < NMO) {
            atomicAdd(&ws[c_pt.wsmap[PART][k]], v);
        } else {
            const int j = k - NMO;
            atomicAdd(&out[c_pt.omap[PART][j]], v * c_pt.oscl[PART][j]);
        }
    }
}

__global__ __launch_bounds__(256, 3) void sht_kernel(const float* __restrict__ pos,
                                                     float* __restrict__ out,
                                                     float* __restrict__ ws, int n, int nblk) {
    // part = blockIdx & 3: stride-256 round-robin (256 % 4 == 0) keeps all
    // resident blocks on a CU in the same part -> I$ locality.
    switch (blockIdx.x & 3) {
        case 0: sht_part<0>(pos, out, ws, n, nblk); break;
        case 1: sht_part<1>(pos, out, ws, n, nblk); break;
        case 2: sht_part<2>(pos, out, ws, n, nblk); break;
        default: sht_part<3>(pos, out, ws, n, nblk); break;
    }

    // Folded combine: the LAST block to finish its moment atomics computes
    // the real outputs from ws (saves the second kernel launch).  Device-
    // scope counter + threadfence (release); reader uses atomic reads, which
    // are coherent across XCDs (per-XCD L2s are not plain-load coherent).
    __shared__ bool s_last;
    __syncthreads();
    if (threadIdx.x == 0) {
        __threadfence();
        const unsigned old = atomicAdd((unsigned*)&ws[CSLOT], 1u);
        s_last = (old == (unsigned)(gridDim.x - 1));
    }
    __syncthreads();
    if (s_last && (int)threadIdx.x < 66) {
        const int t  = (int)threadIdx.x;
        const int nt = c_cb.nt[t];
        float     v  = 0.f;
        for (int j = 0; j < nt; ++j) {
            const float mv = atomicAdd(&ws[c_cb.mIx[t][j]], 0.f);
            const float nv = atomicAdd(&ws[c_cb.nIx[t][j]], 0.f);
            v += c_cb.c[t][j] * (mv - nv);
        }
        out[c_cb.out[t]] = c_cb.scale[t] * v;  // real slots only, disjoint
                                               // from imag atomics' targets
    }
}

extern "C" void kernel_launch(void* const* d_in, const int* in_sizes, int n_in,
                              void* d_out, int out_size, void* d_ws, size_t ws_size,
                              hipStream_t stream) {
    const float* pos = (const float*)d_in[0];
    float* out       = (float*)d_out;
    float* ws        = (float*)d_ws;
    const int n      = in_sizes[0] / 3;  // (N,3) flat -> N points

    // d_out is poisoned before every launch; ws holds moments + done-counter.
    hipMemsetAsync(d_out, 0, (size_t)out_size * sizeof(float), stream);
    hipMemsetAsync(d_ws, 0, WS_FLOATS * sizeof(float), stream);

    const int threads = 256;
    // R7's proven shape: 192 blocks/part x 4 parts = 768 = 3 blocks/CU.
    const int nblk_per_part = 192;
    const int blocks        = NPART * nblk_per_part;  // 768
    sht_kernel<<<blocks, threads, 0, stream>>>(pos, out, ws, n, nblk_per_part);
}

// Round 11
// 126.959 us; speedup vs baseline: 1.0235x; 1.0235x over previous
//
#include <hip/hip_runtime.h>

namespace {

typedef float v2f __attribute__((ext_vector_type(2)));

constexpr int LMAX  = 10;
constexpr int NPART = 4;
// Register-balanced 4-way partition (packed acc = 2 VGPR/slot):
// P0{3,10}=34 acc, P1{2,4,9}=40, P2{1,5,8}=37, P3{0,6,7}=35.
constexpr int PART_OF_L[LMAX + 1] = {3, 2, 1, 0, 1, 2, 3, 3, 2, 1, 0};
constexpr double PI_D = 3.14159265358979323846;

constexpr double dfact(int n) {
    double r = 1.0;
    for (int i = 2; i <= n; ++i) r *= (double)i;
    return r;
}

constexpr double csqrt(double x) {
    if (x <= 0.0) return 0.0;
    double g = x > 1.0 ? x : 1.0;
    for (int i = 0; i < 100; ++i) g = 0.5 * (g + x / g);
    return g;
}

constexpr double FACT[LMAX + 1] = {1., 1., 2., 6., 24., 120., 720., 5040., 40320., 362880., 3628800.};

// ---- global moment layout in workspace (same as R6/R7) --------------------
//   clm_r(l,m) = scale * sum_q c(l,m,q) * (M_{q+m,l} - N_{q,l})
//   M_{p,l} = sum_pts Re(z1^p)^2 * w0 * r^l     (66 entries)
//   N_{q,l} = sum_pts Im(z1^q)^2 * w0 * r^l     (25 entries, q>=1)
constexpr int NM_M = 66;
constexpr int mi(int p, int l) { return l * (l + 1) / 2 + p; }
constexpr int ni_base(int l) {
    int c = 0;
    for (int ll = 0; ll < l; ++ll) c += ll / 2;
    return c;
}
constexpr int ni(int q, int l) { return NM_M + ni_base(l) + (q - 1); }
constexpr int NM_N   = 25;
constexpr int NMOM   = NM_M + NM_N;  // 91
constexpr int ZSLOT  = NMOM;         // always-zero ws slot (index 91)
constexpr int CSLOT  = NMOM + 1;     // done-block counter (index 92)
constexpr int WS_FLOATS = NMOM + 2;  // 93

// ---- per-part helpers ------------------------------------------------------
constexpr int part_lmax(int part) {
    int mx = 0;
    for (int l = 0; l <= LMAX; ++l)
        if (PART_OF_L[l] == part) mx = l;
    return mx;
}
constexpr int nls(int part) {
    int c = 0;
    for (int l = 0; l <= LMAX; ++l)
        if (PART_OF_L[l] == part) ++c;
    return c;
}
constexpr int lidx(int part, int l) {
    int c = 0;
    for (int ll = 0; ll < l; ++ll)
        if (PART_OF_L[ll] == part) ++c;
    return c;
}
constexpr int part_ls(int part, int k) {
    int c = 0;
    for (int l = 0; l <= LMAX; ++l)
        if (PART_OF_L[l] == part) {
            if (c == k) return l;
            ++c;
        }
    return -1;
}
constexpr int nM(int part) {
    int c = 0;
    for (int l = 0; l <= LMAX; ++l)
        if (PART_OF_L[l] == part) c += l + 1;
    return c;
}
constexpr int nN(int part) {
    int c = 0;
    for (int l = 0; l <= LMAX; ++l)
        if (PART_OF_L[l] == part) c += l / 2;
    return c;
}
constexpr int nMom(int part) { return nM(part) + nN(part); }
constexpr int nI(int part) {
    int c = 0;
    for (int l = 0; l <= LMAX; ++l)
        if (PART_OF_L[l] == part) c += l;
    return c;
}
constexpr int nAcc(int part) { return nMom(part) + nI(part); }

constexpr int locM(int part, int p, int l) {
    int c = 0;
    for (int ll = 0; ll < l; ++ll)
        if (PART_OF_L[ll] == part) c += ll + 1;
    return c + p;
}
constexpr int locN(int part, int q, int l) {
    int c = nM(part);
    for (int ll = 0; ll < l; ++ll)
        if (PART_OF_L[ll] == part) c += ll / 2;
    return c + (q - 1);
}
constexpr int locI(int part, int m, int l) {
    int c = nMom(part);
    for (int ll = 0; ll < l; ++ll)
        if (PART_OF_L[ll] == part) c += ll;
    return c + (m - 1);
}

constexpr int MAXMOM = 25;  // P1: 18 M + 7 N
constexpr int MAXIMG = 15;  // P1

// Horner coefficient for the collapsed imag sum: (-1)^q / ((q+m)! q! (l-m-2q)!)
constexpr float ci_coef(int l, int m, int q) {
    const double c = 1.0 / (FACT[q + m] * FACT[q] * FACT[l - m - 2 * q]);
    return (q & 1) ? (float)(-c) : (float)c;
}

struct PartTab {
    short wsmap[NPART][MAXMOM];  // local moment slot -> global ws index
    int   omap[NPART][MAXIMG];   // local imag slot -> out index
    float oscl[NPART][MAXIMG];   // imag output scale (sqrt2*(-1)^m, T==1 fold)
};

constexpr PartTab make_pt() {
    PartTab t{};
    for (int part = 0; part < NPART; ++part) {
        for (int l = 0; l <= LMAX; ++l) {
            if (PART_OF_L[l] != part) continue;
            for (int p = 0; p <= l; ++p) t.wsmap[part][locM(part, p, l)] = (short)mi(p, l);
            for (int q = 1; q <= l / 2; ++q) t.wsmap[part][locN(part, q, l)] = (short)ni(q, l);
            for (int m = 1; m <= l; ++m) {
                const int    k     = locI(part, m, l) - nMom(part);
                const double scale = csqrt(dfact(l + m) * dfact(l - m)) * csqrt((2 * l + 1) / (4.0 * PI_D));
                const double f     = csqrt(2.0) * ((m & 1) ? -1.0 : 1.0);
                const double fold  = ((l - m) <= 1) ? 1.0 / (dfact(m) * dfact(l - m)) : 1.0;
                t.omap[part][k] = l * l + l - m;
                t.oscl[part][k] = (float)(f * scale * fold);
            }
        }
    }
    return t;
}

// Combine table: per real output slot, the q-term list over moments.
struct CombTab {
    int   out[66];
    float scale[66];
    int   nt[66];
    float c[66][6];
    short mIx[66][6];
    short nIx[66][6];
};

constexpr CombTab make_comb() {
    CombTab t{};
    int k = 0;
    for (int l = 0; l <= LMAX; ++l) {
        for (int m = 0; m <= l; ++m) {
            const double scale = csqrt(dfact(l + m) * dfact(l - m)) * csqrt((2 * l + 1) / (4.0 * PI_D));
            const double f     = (m == 0) ? 1.0 : csqrt(2.0) * ((m & 1) ? -1.0 : 1.0);
            t.out[k]   = (m == 0) ? l * l + l : l * l + l + m;
            t.scale[k] = (float)(f * scale);
            const int Q = (l - m) / 2;
            t.nt[k]     = Q + 1;
            for (int q = 0; q <= Q; ++q) {
                const double c = 1.0 / (FACT[q + m] * FACT[q] * FACT[l - m - 2 * q]);
                t.c[k][q]   = (float)c;
                t.mIx[k][q] = (short)mi(q + m, l);
                t.nIx[k][q] = (short)(q >= 1 ? ni(q, l) : ZSLOT);
            }
            ++k;
        }
    }
    return t;
}

__constant__ PartTab c_pt = make_pt();
__constant__ CombTab c_cb = make_comb();

// Load the point pair {2*ip, 2*ip+1} into packed X/Y/Z (point j in half j).
// OOB points zero-fill; zero points contribute exactly zero (w0 = 0).
__device__ __forceinline__ void load_pair(const float* __restrict__ pos, int ip, int n,
                                          v2f& X, v2f& Y, v2f& Z) {
    const int i0 = 2 * ip;
    if (i0 + 1 < n) {
        const float2* p2 = reinterpret_cast<const float2*>(pos + 3 * i0);
        const float2  a = p2[0], b = p2[1], d = p2[2];
        X.x = a.x; X.y = b.y;
        Y.x = a.y; Y.y = d.x;
        Z.x = b.x; Z.y = d.y;
    } else if (i0 < n) {
        X.x = pos[3 * i0]; Y.x = pos[3 * i0 + 1]; Z.x = pos[3 * i0 + 2];
        X.y = 0.f; Y.y = 0.f; Z.y = 0.f;
    } else {
        X = (v2f)(0.f); Y = (v2f)(0.f); Z = (v2f)(0.f);
    }
}

}  // namespace

// R7/R9's exact main loop (plain v2f codegen — R10 proved asm-forced v_pk_*
// adds mov traffic and defeats the scheduler: 44 -> 64.6 us at equal issue
// count; the compiler's own lowering is the floor for this structure).
// Moment factorization for the real part (R6), packed 2-pt-per-thread (R7),
// 4 register-balanced parts, serial z-chain, 3 blocks/CU.
template <int PART>
__device__ __forceinline__ void sht_part(const float* __restrict__ pos, float* __restrict__ out,
                                         float* __restrict__ ws, int n, int nblk) {
    constexpr int PL  = part_lmax(PART);
    constexpr int QX  = PL / 2;
    constexpr int NL  = nls(PART);
    constexpr int NMO = nMom(PART);
    constexpr int NAC = nAcc(PART);

    v2f acc[NAC];
#pragma unroll
    for (int k = 0; k < NAC; ++k) acc[k] = (v2f)(0.f);

    const int bid    = (int)(blockIdx.x >> 2);
    const int tid    = bid * 256 + (int)threadIdx.x;
    const int stride = nblk * 256;  // in pairs
    const int npair  = (n + 1) >> 1;

    v2f X, Y, Z;
    int ip = tid;
    load_pair(pos, ip, n, X, Y, Z);

    while (ip < npair) {
        // software-pipelined prefetch of the next pair
        const int inext = ip + stride;
        v2f       nX, nY, nZ;
        load_pair(pos, inext, n, nX, nY, nZ);

        const v2f r2 = X * X + Y * Y + Z * Z;
        v2f       nrm;
        nrm.x = sqrtf(r2.x);
        nrm.y = sqrtf(r2.y);
        v2f w0;
        w0.x = (nrm.x > 0.f) ? Z.x : 0.f;  // x0 * mask
        w0.y = (nrm.y > 0.f) ? Z.y : 0.f;

        const v2f ar  = -0.5f * X;
        const v2f ai  = -0.5f * Y;
        const v2f rho = ar * ar + ai * ai;  // |z1|^2

        // wl[k] = w0 * nrm^l via binary decomposition (parts mix parities).
        v2f wl[NL];
        {
            const v2f p2v = nrm * nrm;
            const v2f p4v = p2v * p2v;
            const v2f p8v = p4v * p4v;
#pragma unroll
            for (int k = 0; k < NL; ++k) {
                const int l = part_ls(PART, k);  // compile-time
                v2f       t = w0;
                if (l & 1) t = t * nrm;
                if (l & 2) t = t * p2v;
                if (l & 4) t = t * p4v;
                if (l & 8) t = t * p8v;
                wl[k] = t;
            }
        }

        // p-major rolling powers of z1: consume sr_p/si_p immediately into
        // moment accumulators; only zi[] is tabled (needed by imag pass).
        v2f zi[PL + 1];
        v2f zrc = (v2f)(1.f), zic = (v2f)(0.f);
#pragma unroll
        for (int p = 0; p <= PL; ++p) {
            if (p) {
                const v2f nr = ar * zrc - ai * zic;
                zic          = ar * zic + ai * zrc;
                zrc          = nr;
            }
            zi[p] = zic;
            const v2f srp = zrc * zrc;
#pragma unroll
            for (int l = 0; l <= LMAX; ++l)
                if (PART_OF_L[l] == PART && l >= p)
                    acc[locM(PART, p, l)] += srp * wl[lidx(PART, l)];
            if (p >= 1 && p <= QX) {
                const v2f sip = zic * zic;
#pragma unroll
                for (int l = 0; l <= LMAX; ++l)
                    if (PART_OF_L[l] == PART && l >= 2 * p)
                        acc[locN(PART, p, l)] += sip * wl[lidx(PART, l)];
            }
        }

        // imag pass: acc_I(l,m) += zi[m] * Horner_q(+-c * rho^q) * wrl
#pragma unroll
        for (int l = 0; l <= LMAX; ++l) {
            if (PART_OF_L[l] != PART) continue;
            const v2f wrl = wl[lidx(PART, l)];
#pragma unroll
            for (int m = 1; m <= l; ++m) {
                const int Q = (l - m) >> 1;
                if (Q == 0) {
                    acc[locI(PART, m, l)] += zi[m] * wrl;  // coeff in oscl
                } else {
                    v2f tq = (v2f)(ci_coef(l, m, Q));
#pragma unroll
                    for (int q = Q - 1; q >= 0; --q) tq = tq * rho + ci_coef(l, m, q);
                    acc[locI(PART, m, l)] += (tq * zi[m]) * wrl;
                }
            }
        }

        ip = inext;
        X  = nX;
        Y  = nY;
        Z  = nZ;
    }

    // Fold packed halves, then wave shuffle reduction, then cross-wave LDS.
    __shared__ float red[4][NAC];
    const int lane = threadIdx.x & 63;
    const int wav  = threadIdx.x >> 6;
#pragma unroll
    for (int k = 0; k < NAC; ++k) {
        float v = acc[k].x + acc[k].y;
#pragma unroll
        for (int off = 32; off > 0; off >>= 1) v += __shfl_down(v, off, 64);
        if (lane == 0) red[wav][k] = v;
    }
    __syncthreads();
    if ((int)threadIdx.x < NAC) {
        const int   k = (int)threadIdx.x;
        const float v = red[0][k] + red[1][k] + red[2][k] + red[3][k];
        if (k < NMO) {
            atomicAdd(&ws[c_pt.wsmap[PART][k]], v);
        } else {
            const int j = k - NMO;
            atomicAdd(&out[c_pt.omap[PART][j]], v * c_pt.oscl[PART][j]);
        }
    }
}

__global__ __launch_bounds__(256, 3) void sht_kernel(const float* __restrict__ pos,
                                                     float* __restrict__ out,
                                                     float* __restrict__ ws, int n, int nblk) {
    // part = blockIdx & 3: stride-256 round-robin (256 % 4 == 0) keeps all
    // resident blocks on a CU in the same part -> I$ locality.
    switch (blockIdx.x & 3) {
        case 0: sht_part<0>(pos, out, ws, n, nblk); break;
        case 1: sht_part<1>(pos, out, ws, n, nblk); break;
        case 2: sht_part<2>(pos, out, ws, n, nblk); break;
        default: sht_part<3>(pos, out, ws, n, nblk); break;
    }

    // Folded combine (kept from R10 — independent of its asm regression):
    // the LAST block to finish its moment atomics computes the real outputs
    // from ws, saving the second serialized launch.  Device-scope counter +
    // threadfence (release); reader uses atomic reads (coherent across the
    // non-coherent per-XCD L2s).
    __shared__ bool s_last;
    __syncthreads();
    if (threadIdx.x == 0) {
        __threadfence();
        const unsigned old = atomicAdd((unsigned*)&ws[CSLOT], 1u);
        s_last = (old == (unsigned)(gridDim.x - 1));
    }
    __syncthreads();
    if (s_last && (int)threadIdx.x < 66) {
        const int t  = (int)threadIdx.x;
        const int nt = c_cb.nt[t];
        float     v  = 0.f;
        for (int j = 0; j < nt; ++j) {
            const float mv = atomicAdd(&ws[c_cb.mIx[t][j]], 0.f);
            const float nv = atomicAdd(&ws[c_cb.nIx[t][j]], 0.f);
            v += c_cb.c[t][j] * (mv - nv);
        }
        out[c_cb.out[t]] = c_cb.scale[t] * v;  // real slots only, disjoint
                                               // from imag atomics' targets
    }
}

extern "C" void kernel_launch(void* const* d_in, const int* in_sizes, int n_in,
                              void* d_out, int out_size, void* d_ws, size_t ws_size,
                              hipStream_t stream) {
    const float* pos = (const float*)d_in[0];
    float* out       = (float*)d_out;
    float* ws        = (float*)d_ws;
    const int n      = in_sizes[0] / 3;  // (N,3) flat -> N points

    // d_out is poisoned before every launch; ws holds moments + done-counter.
    hipMemsetAsync(d_out, 0, (size_t)out_size * sizeof(float), stream);
    hipMemsetAsync(d_ws, 0, WS_FLOATS * sizeof(float), stream);

    const int threads = 256;
    // R7's proven shape: 192 blocks/part x 4 parts = 768 = 3 blocks/CU.
    const int nblk_per_part = 192;
    const int blocks        = NPART * nblk_per_part;  // 768
    sht_kernel<<<blocks, threads, 0, stream>>>(pos, out, ws, n, nblk_per_part);
}

// Round 12
// 109.118 us; speedup vs baseline: 1.1908x; 1.1635x over previous
//
#include <hip/hip_runtime.h>

namespace {

typedef float v2f __attribute__((ext_vector_type(2)));

constexpr int LMAX  = 10;
constexpr int NPART = 4;
// Register-balanced 4-way partition (packed acc = 2 VGPR/slot):
// P0{3,10}=34 acc, P1{2,4,9}=40, P2{1,5,8}=37, P3{0,6,7}=35.
constexpr int PART_OF_L[LMAX + 1] = {3, 2, 1, 0, 1, 2, 3, 3, 2, 1, 0};
constexpr double PI_D = 3.14159265358979323846;

constexpr double dfact(int n) {
    double r = 1.0;
    for (int i = 2; i <= n; ++i) r *= (double)i;
    return r;
}

constexpr double csqrt(double x) {
    if (x <= 0.0) return 0.0;
    double g = x > 1.0 ? x : 1.0;
    for (int i = 0; i < 100; ++i) g = 0.5 * (g + x / g);
    return g;
}

constexpr double FACT[LMAX + 1] = {1., 1., 2., 6., 24., 120., 720., 5040., 40320., 362880., 3628800.};

// ---- global moment layout in workspace ------------------------------------
//   clm_r(l,m) = scale * sum_q c(l,m,q) * (M_{q+m,l} - N_{q,l})
//   M_{p,l} = sum_pts Re(z1^p)^2 * w0 * r^l     (66 entries)
//   N_{q,l} = sum_pts Im(z1^q)^2 * w0 * r^l     (25 entries, q>=1)
constexpr int NM_M = 66;
constexpr int mi(int p, int l) { return l * (l + 1) / 2 + p; }
constexpr int ni_base(int l) {
    int c = 0;
    for (int ll = 0; ll < l; ++ll) c += ll / 2;
    return c;
}
constexpr int ni(int q, int l) { return NM_M + ni_base(l) + (q - 1); }
constexpr int NM_N  = 25;
constexpr int NMOM  = NM_M + NM_N;  // 91
constexpr int ZSLOT = NMOM;         // always-zero ws slot
constexpr int WS_FLOATS = NMOM + 1; // 92

// ---- per-part helpers ------------------------------------------------------
constexpr int part_lmax(int part) {
    int mx = 0;
    for (int l = 0; l <= LMAX; ++l)
        if (PART_OF_L[l] == part) mx = l;
    return mx;
}
constexpr int nls(int part) {
    int c = 0;
    for (int l = 0; l <= LMAX; ++l)
        if (PART_OF_L[l] == part) ++c;
    return c;
}
constexpr int lidx(int part, int l) {
    int c = 0;
    for (int ll = 0; ll < l; ++ll)
        if (PART_OF_L[ll] == part) ++c;
    return c;
}
constexpr int part_ls(int part, int k) {
    int c = 0;
    for (int l = 0; l <= LMAX; ++l)
        if (PART_OF_L[l] == part) {
            if (c == k) return l;
            ++c;
        }
    return -1;
}
constexpr int nM(int part) {
    int c = 0;
    for (int l = 0; l <= LMAX; ++l)
        if (PART_OF_L[l] == part) c += l + 1;
    return c;
}
constexpr int nN(int part) {
    int c = 0;
    for (int l = 0; l <= LMAX; ++l)
        if (PART_OF_L[l] == part) c += l / 2;
    return c;
}
constexpr int nMom(int part) { return nM(part) + nN(part); }
constexpr int nI(int part) {
    int c = 0;
    for (int l = 0; l <= LMAX; ++l)
        if (PART_OF_L[l] == part) c += l;
    return c;
}
constexpr int nAcc(int part) { return nMom(part) + nI(part); }

constexpr int locM(int part, int p, int l) {
    int c = 0;
    for (int ll = 0; ll < l; ++ll)
        if (PART_OF_L[ll] == part) c += ll + 1;
    return c + p;
}
constexpr int locN(int part, int q, int l) {
    int c = nM(part);
    for (int ll = 0; ll < l; ++ll)
        if (PART_OF_L[ll] == part) c += ll / 2;
    return c + (q - 1);
}
constexpr int locI(int part, int m, int l) {
    int c = nMom(part);
    for (int ll = 0; ll < l; ++ll)
        if (PART_OF_L[ll] == part) c += ll;
    return c + (m - 1);
}

constexpr int MAXMOM = 25;  // P1: 18 M + 7 N
constexpr int MAXIMG = 15;  // P1

// Horner coefficient for the collapsed imag sum: (-1)^q / ((q+m)! q! (l-m-2q)!)
constexpr float ci_coef(int l, int m, int q) {
    const double c = 1.0 / (FACT[q + m] * FACT[q] * FACT[l - m - 2 * q]);
    return (q & 1) ? (float)(-c) : (float)c;
}

struct PartTab {
    short wsmap[NPART][MAXMOM];  // local moment slot -> global ws index
    int   omap[NPART][MAXIMG];   // local imag slot -> out index
    float oscl[NPART][MAXIMG];   // imag output scale (sqrt2*(-1)^m, T==1 fold)
};

constexpr PartTab make_pt() {
    PartTab t{};
    for (int part = 0; part < NPART; ++part) {
        for (int l = 0; l <= LMAX; ++l) {
            if (PART_OF_L[l] != part) continue;
            for (int p = 0; p <= l; ++p) t.wsmap[part][locM(part, p, l)] = (short)mi(p, l);
            for (int q = 1; q <= l / 2; ++q) t.wsmap[part][locN(part, q, l)] = (short)ni(q, l);
            for (int m = 1; m <= l; ++m) {
                const int    k     = locI(part, m, l) - nMom(part);
                const double scale = csqrt(dfact(l + m) * dfact(l - m)) * csqrt((2 * l + 1) / (4.0 * PI_D));
                const double f     = csqrt(2.0) * ((m & 1) ? -1.0 : 1.0);
                const double fold  = ((l - m) <= 1) ? 1.0 / (dfact(m) * dfact(l - m)) : 1.0;
                t.omap[part][k] = l * l + l - m;
                t.oscl[part][k] = (float)(f * scale * fold);
            }
        }
    }
    return t;
}

// Combine-kernel table: per real output slot, the q-term list over moments.
struct CombTab {
    int   out[66];
    float scale[66];
    int   nt[66];
    float c[66][6];
    short mIx[66][6];
    short nIx[66][6];
};

constexpr CombTab make_comb() {
    CombTab t{};
    int k = 0;
    for (int l = 0; l <= LMAX; ++l) {
        for (int m = 0; m <= l; ++m) {
            const double scale = csqrt(dfact(l + m) * dfact(l - m)) * csqrt((2 * l + 1) / (4.0 * PI_D));
            const double f     = (m == 0) ? 1.0 : csqrt(2.0) * ((m & 1) ? -1.0 : 1.0);
            t.out[k]   = (m == 0) ? l * l + l : l * l + l + m;
            t.scale[k] = (float)(f * scale);
            const int Q = (l - m) / 2;
            t.nt[k]     = Q + 1;
            for (int q = 0; q <= Q; ++q) {
                const double c = 1.0 / (FACT[q + m] * FACT[q] * FACT[l - m - 2 * q]);
                t.c[k][q]   = (float)c;
                t.mIx[k][q] = (short)mi(q + m, l);
                t.nIx[k][q] = (short)(q >= 1 ? ni(q, l) : ZSLOT);
            }
            ++k;
        }
    }
    return t;
}

__constant__ PartTab c_pt = make_pt();
__constant__ CombTab c_cb = make_comb();

// Load the point pair {2*ip, 2*ip+1} into packed X/Y/Z (point j in half j).
// OOB points zero-fill; zero points contribute exactly zero (w0 = 0).
__device__ __forceinline__ void load_pair(const float* __restrict__ pos, int ip, int n,
                                          v2f& X, v2f& Y, v2f& Z) {
    const int i0 = 2 * ip;
    if (i0 + 1 < n) {
        const float2* p2 = reinterpret_cast<const float2*>(pos + 3 * i0);
        const float2  a = p2[0], b = p2[1], d = p2[2];
        X.x = a.x; X.y = b.y;
        Y.x = a.y; Y.y = d.x;
        Z.x = b.x; Z.y = d.y;
    } else if (i0 < n) {
        X.x = pos[3 * i0]; Y.x = pos[3 * i0 + 1]; Z.x = pos[3 * i0 + 2];
        X.y = 0.f; Y.y = 0.f; Z.y = 0.f;
    } else {
        X = (v2f)(0.f); Y = (v2f)(0.f); Z = (v2f)(0.f);
    }
}

}  // namespace

// R9's exact configuration — the measured best (kernel 44.2 us, e2e 108.8):
// moment factorization (R6) + packed 2-pt/thread plain-v2f codegen (R7),
// 4 register-balanced parts, serial z-chain, 3 blocks/CU, SEPARATE tiny
// combine kernel.  R10/R11 isolated the folded last-block combine as a
// ~20 us regression (cross-XCD __threadfence publish is an L2 writeback per
// block + serialized same-address RMWs — far costlier than a second launch);
// R10 also showed asm-forced v_pk_* defeats the scheduler.  Both reverted.
template <int PART>
__device__ __forceinline__ void sht_part(const float* __restrict__ pos, float* __restrict__ out,
                                         float* __restrict__ ws, int n, int nblk) {
    constexpr int PL  = part_lmax(PART);
    constexpr int QX  = PL / 2;
    constexpr int NL  = nls(PART);
    constexpr int NMO = nMom(PART);
    constexpr int NAC = nAcc(PART);

    v2f acc[NAC];
#pragma unroll
    for (int k = 0; k < NAC; ++k) acc[k] = (v2f)(0.f);

    const int bid    = (int)(blockIdx.x >> 2);
    const int tid    = bid * 256 + (int)threadIdx.x;
    const int stride = nblk * 256;  // in pairs
    const int npair  = (n + 1) >> 1;

    v2f X, Y, Z;
    int ip = tid;
    load_pair(pos, ip, n, X, Y, Z);

    while (ip < npair) {
        // software-pipelined prefetch of the next pair
        const int inext = ip + stride;
        v2f       nX, nY, nZ;
        load_pair(pos, inext, n, nX, nY, nZ);

        const v2f r2 = X * X + Y * Y + Z * Z;
        v2f       nrm;
        nrm.x = sqrtf(r2.x);
        nrm.y = sqrtf(r2.y);
        v2f w0;
        w0.x = (nrm.x > 0.f) ? Z.x : 0.f;  // x0 * mask
        w0.y = (nrm.y > 0.f) ? Z.y : 0.f;

        const v2f ar  = -0.5f * X;
        const v2f ai  = -0.5f * Y;
        const v2f rho = ar * ar + ai * ai;  // |z1|^2

        // wl[k] = w0 * nrm^l via binary decomposition (parts mix parities).
        v2f wl[NL];
        {
            const v2f p2v = nrm * nrm;
            const v2f p4v = p2v * p2v;
            const v2f p8v = p4v * p4v;
#pragma unroll
            for (int k = 0; k < NL; ++k) {
                const int l = part_ls(PART, k);  // compile-time
                v2f       t = w0;
                if (l & 1) t = t * nrm;
                if (l & 2) t = t * p2v;
                if (l & 4) t = t * p4v;
                if (l & 8) t = t * p8v;
                wl[k] = t;
            }
        }

        // p-major rolling powers of z1: consume sr_p/si_p immediately into
        // moment accumulators; only zi[] is tabled (needed by imag pass).
        v2f zi[PL + 1];
        v2f zrc = (v2f)(1.f), zic = (v2f)(0.f);
#pragma unroll
        for (int p = 0; p <= PL; ++p) {
            if (p) {
                const v2f nr = ar * zrc - ai * zic;
                zic          = ar * zic + ai * zrc;
                zrc          = nr;
            }
            zi[p] = zic;
            const v2f srp = zrc * zrc;
#pragma unroll
            for (int l = 0; l <= LMAX; ++l)
                if (PART_OF_L[l] == PART && l >= p)
                    acc[locM(PART, p, l)] += srp * wl[lidx(PART, l)];
            if (p >= 1 && p <= QX) {
                const v2f sip = zic * zic;
#pragma unroll
                for (int l = 0; l <= LMAX; ++l)
                    if (PART_OF_L[l] == PART && l >= 2 * p)
                        acc[locN(PART, p, l)] += sip * wl[lidx(PART, l)];
            }
        }

        // imag pass: acc_I(l,m) += zi[m] * Horner_q(+-c * rho^q) * wrl
#pragma unroll
        for (int l = 0; l <= LMAX; ++l) {
            if (PART_OF_L[l] != PART) continue;
            const v2f wrl = wl[lidx(PART, l)];
#pragma unroll
            for (int m = 1; m <= l; ++m) {
                const int Q = (l - m) >> 1;
                if (Q == 0) {
                    acc[locI(PART, m, l)] += zi[m] * wrl;  // coeff in oscl
                } else {
                    v2f tq = (v2f)(ci_coef(l, m, Q));
#pragma unroll
                    for (int q = Q - 1; q >= 0; --q) tq = tq * rho + ci_coef(l, m, q);
                    acc[locI(PART, m, l)] += (tq * zi[m]) * wrl;
                }
            }
        }

        ip = inext;
        X  = nX;
        Y  = nY;
        Z  = nZ;
    }

    // Fold packed halves, then wave shuffle reduction, then cross-wave LDS.
    __shared__ float red[4][NAC];
    const int lane = threadIdx.x & 63;
    const int wav  = threadIdx.x >> 6;
#pragma unroll
    for (int k = 0; k < NAC; ++k) {
        float v = acc[k].x + acc[k].y;
#pragma unroll
        for (int off = 32; off > 0; off >>= 1) v += __shfl_down(v, off, 64);
        if (lane == 0) red[wav][k] = v;
    }
    __syncthreads();
    if ((int)threadIdx.x < NAC) {
        const int   k = (int)threadIdx.x;
        const float v = red[0][k] + red[1][k] + red[2][k] + red[3][k];
        if (k < NMO) {
            atomicAdd(&ws[c_pt.wsmap[PART][k]], v);
        } else {
            const int j = k - NMO;
            atomicAdd(&out[c_pt.omap[PART][j]], v * c_pt.oscl[PART][j]);
        }
    }
}

__global__ __launch_bounds__(256, 3) void sht_kernel(const float* __restrict__ pos,
                                                     float* __restrict__ out,
                                                     float* __restrict__ ws, int n, int nblk) {
    // part = blockIdx & 3: stride-256 round-robin (256 % 4 == 0) keeps all
    // resident blocks on a CU in the same part -> I$ locality.
    switch (blockIdx.x & 3) {
        case 0: sht_part<0>(pos, out, ws, n, nblk); break;
        case 1: sht_part<1>(pos, out, ws, n, nblk); break;
        case 2: sht_part<2>(pos, out, ws, n, nblk); break;
        default: sht_part<3>(pos, out, ws, n, nblk); break;
    }
}

// Tiny in-stream combine: real outputs from moments.  Writes only real slots,
// disjoint from the imag atomics' targets; stream order puts it after.
// (R10/R11: folding this into the main kernel via last-block + threadfence
//  costs ~20 us — the separate launch is effectively free.)
__global__ void sht_combine(const float* __restrict__ ws, float* __restrict__ out) {
    const int t = (int)threadIdx.x;
    if (t < 66) {
        const int nt = c_cb.nt[t];
        float     v  = 0.f;
        for (int j = 0; j < nt; ++j)
            v += c_cb.c[t][j] * (ws[c_cb.mIx[t][j]] - ws[c_cb.nIx[t][j]]);
        out[c_cb.out[t]] = c_cb.scale[t] * v;
    }
}

extern "C" void kernel_launch(void* const* d_in, const int* in_sizes, int n_in,
                              void* d_out, int out_size, void* d_ws, size_t ws_size,
                              hipStream_t stream) {
    const float* pos = (const float*)d_in[0];
    float* out       = (float*)d_out;
    float* ws        = (float*)d_ws;
    const int n      = in_sizes[0] / 3;  // (N,3) flat -> N points

    // d_out is poisoned before every launch; ws holds the moment accumulators.
    hipMemsetAsync(d_out, 0, (size_t)out_size * sizeof(float), stream);
    hipMemsetAsync(d_ws, 0, WS_FLOATS * sizeof(float), stream);

    const int threads = 256;
    // R7/R9's proven shape: 192 blocks/part x 4 parts = 768 = 3 blocks/CU.
    const int nblk_per_part = 192;
    const int blocks        = NPART * nblk_per_part;  // 768
    sht_kernel<<<blocks, threads, 0, stream>>>(pos, out, ws, n, nblk_per_part);
    sht_combine<<<1, 128, 0, stream>>>(ws, out);
}